// Round 4
// baseline (1562.142 us; speedup 1.0000x reference)
//
#include <hip/hip_runtime.h>

#define BB 1024
#define TT 512
#define II 128
#define HH 64
#define G4 256   // 4*H
#define EE 128
#define CC 100
#define NB 4     // batch rows per block; 256 blocks = 1 per CU
#define NTH 1024 // 16 waves -> 4 waves/SIMD (the round-3 fix: was 2)
#define SK 8     // split-K eighths (was 4; forced by 80-float weight budget)

typedef float f2 __attribute__((ext_vector_type(2)));
typedef float f4 __attribute__((ext_vector_type(4)));

__device__ __forceinline__ float sigm(float v) { return 1.f / (1.f + __expf(-v)); }
__device__ __forceinline__ float tanh_f(float v) {
    v = fminf(fmaxf(v, -15.f), 15.f);   // avoid inf/inf NaN
    float e = __expf(2.f * v);
    return (e - 1.f) / (e + 1.f);
}

// Round-6: occupancy attack. r3 counters: Occupancy 23% (8 waves/CU, grid-
// limited), VALUBusy 60%, ~40% idle -- 2 waves/SIMD can't hide ds_read +
// combine latency. Per-thread weights = 81920/NTH, so NTH 512->1024 halves
// them to 80 floats -> fits 128-VGPR budget -> __launch_bounds__(1024,4)
// = 4 waves/SIMD. Thread (e,r) owns gate rows {r, r+128} and K-eighth e
// (2-row ownership keeps 8 MACs per broadcast LDS read -> per-CU LDS issue
// unchanged). Split-K widens 4->8: zp = 2x32KB, combine sums 8 partials
// (biases moved to registers to compensate). Cross-layer pipeline kept:
// iter t computes z0(t) and z1(t-1) in one GEMV phase, one fused combine
// (waves 0-3 -> cell0, waves 4-7 -> cell1), 2 barriers/iter.
__global__ __launch_bounds__(NTH, 4)
void lstm2_persistent(const float* __restrict__ x,
                      const float* __restrict__ Wih0, const float* __restrict__ Whh0,
                      const float* __restrict__ bih0, const float* __restrict__ bhh0,
                      const float* __restrict__ Wih1, const float* __restrict__ Whh1,
                      const float* __restrict__ bih1, const float* __restrict__ bhh1,
                      float* __restrict__ hlast)
{
    __shared__ float xs[2][NB][II];      // double-buffered x tile (4 KB)
    __shared__ float h0s[NB][HH];        // layer-0 hidden h0(t-1)  (1 KB)
    __shared__ float h1s[NB][HH];        // layer-1 hidden h1(t-2)  (1 KB)
    __shared__ float zp0[SK][NB][G4];    // layer-0 split-K partials (32 KB)
    __shared__ float zp1[SK][NB][G4];    // layer-1 split-K partials (32 KB)
    // total 70 KB static LDS -- OK on gfx950 (160 KB/workgroup)

    const int tid = threadIdx.x;
    const int e   = tid >> 7;            // K-eighth 0..7 (wave-uniform)
    const int r   = tid & 127;           // row-pair id: owns gate rows r, r+128
    const int b0  = blockIdx.x * NB;

    // ---- weight fragments: 40 float2 = 80 floats, register-resident ----
    f2 w0a[8], w0b[8];   // Wih0 rows r / r+128, cols [e*16, e*16+16)
    f2 h0a[4], h0b[4];   // Whh0 rows r / r+128, cols [e*8, e*8+8)
    f2 u1a[4], u1b[4];   // Wih1 rows r / r+128, cols [e*8, e*8+8)
    f2 v1a[4], v1b[4];   // Whh1 rows r / r+128, cols [e*8, e*8+8)

#define LOADW(dst, src, n4)                                          \
    do {                                                             \
        const f4* _s = (const f4*)(src);                             \
        _Pragma("unroll")                                            \
        for (int k = 0; k < (n4); ++k) {                             \
            f4 t = _s[k];                                            \
            dst[2*k]   = (f2){t.x, t.y};                             \
            dst[2*k+1] = (f2){t.z, t.w};                             \
        }                                                            \
    } while (0)

    LOADW(w0a, Wih0 + (size_t)r         * II + e * 16, 4);
    LOADW(w0b, Wih0 + (size_t)(r + 128) * II + e * 16, 4);
    LOADW(h0a, Whh0 + (size_t)r         * HH + e * 8, 2);
    LOADW(h0b, Whh0 + (size_t)(r + 128) * HH + e * 8, 2);
    LOADW(u1a, Wih1 + (size_t)r         * HH + e * 8, 2);
    LOADW(u1b, Wih1 + (size_t)(r + 128) * HH + e * 8, 2);
    LOADW(v1a, Whh1 + (size_t)r         * HH + e * 8, 2);
    LOADW(v1b, Whh1 + (size_t)(r + 128) * HH + e * 8, 2);
#undef LOADW

#define PIN(arr, n)                                                  \
    _Pragma("unroll")                                                \
    for (int _i = 0; _i < (n); ++_i) asm volatile("" : "+v"(arr[_i]))

    // combine roles: tid<256 -> layer-0 cell (cb,cj); tid in [256,512) ->
    // layer-1 cell; tid>=512 idle in combine. lay is wave-uniform.
    const int lay = tid >> 8;            // 0 / 1 valid for tid<512
    const int cb  = (tid >> 6) & 3, cj = tid & 63;
    float c_reg = 0.f;
    float bi_r = 0.f, bf_r = 0.f, bg_r = 0.f, bo_r = 0.f;
    if (tid < 512) {                     // fold biases into registers (no LDS)
        const float* bih = lay ? bih1 : bih0;
        const float* bhh = lay ? bhh1 : bhh0;
        bi_r = bih[cj]       + bhh[cj];
        bf_r = bih[64 + cj]  + bhh[64 + cj];
        bg_r = bih[128 + cj] + bhh[128 + cj];
        bo_r = bih[192 + cj] + bhh[192 + cj];
    }

    if (tid < 256) {
        h0s[(tid >> 6) & 3][tid & 63] = 0.f;
        h1s[(tid >> 6) & 3][tid & 63] = 0.f;
    }

    // x staging: threads tid<512: (lrow,lcol) loads x[b0+lrow][t][lcol]
    const int lrow = (tid >> 7) & 3, lcol = tid & 127;
    const float* xrow = x + ((size_t)(b0 + lrow) * TT) * II + lcol;
    float pre = 0.f;
    if (tid < NB * II) {
        xs[0][lrow][lcol] = xrow[0];
        pre = xrow[II];                  // x(1)
    }

    __syncthreads();

    // Pipelined: iteration t computes z0(t) [t<TT] and z1(t-1) [t>=1], then
    // one fused combine. Invariant at loop top: h0s=h0(t-1), h1s=h1(t-2).
    for (int t = 0; t <= TT; ++t) {
        const int cur = t & 1, nxt = cur ^ 1;

        PIN(w0a, 8); PIN(w0b, 8);
        PIN(h0a, 4); PIN(h0b, 4);
        PIN(u1a, 4); PIN(u1b, 4);
        PIN(v1a, 4); PIN(v1b, 4);

        // ---- GEMV phase ----
        if (t < TT) {   // layer-0 partials for step t
            #pragma unroll
            for (int b = 0; b < NB; ++b) {
                f2 aA = (f2){0.f, 0.f}, aB = (f2){0.f, 0.f};
                const f4* xv = (const f4*)&xs[cur][b][e * 16];
                #pragma unroll
                for (int k = 0; k < 4; ++k) {
                    f4 v = xv[k];                       // wave-uniform -> LDS broadcast
                    f2 lo = (f2){v.x, v.y}, hi = (f2){v.z, v.w};
                    aA += w0a[2*k] * lo;  aA += w0a[2*k+1] * hi;
                    aB += w0b[2*k] * lo;  aB += w0b[2*k+1] * hi;
                }
                const f4* hv = (const f4*)&h0s[b][e * 8];
                #pragma unroll
                for (int k = 0; k < 2; ++k) {
                    f4 v = hv[k];
                    f2 lo = (f2){v.x, v.y}, hi = (f2){v.z, v.w};
                    aA += h0a[2*k] * lo;  aA += h0a[2*k+1] * hi;
                    aB += h0b[2*k] * lo;  aB += h0b[2*k+1] * hi;
                }
                zp0[e][b][r]       = aA.x + aA.y;
                zp0[e][b][r + 128] = aB.x + aB.y;
            }
        }
        if (t >= 1) {   // layer-1 partials for step t-1 (h0(t-1), h1(t-2))
            #pragma unroll
            for (int b = 0; b < NB; ++b) {
                f2 aA = (f2){0.f, 0.f}, aB = (f2){0.f, 0.f};
                const f4* hv0 = (const f4*)&h0s[b][e * 8];
                #pragma unroll
                for (int k = 0; k < 2; ++k) {
                    f4 v = hv0[k];
                    f2 lo = (f2){v.x, v.y}, hi = (f2){v.z, v.w};
                    aA += u1a[2*k] * lo;  aA += u1a[2*k+1] * hi;
                    aB += u1b[2*k] * lo;  aB += u1b[2*k+1] * hi;
                }
                const f4* hv1 = (const f4*)&h1s[b][e * 8];
                #pragma unroll
                for (int k = 0; k < 2; ++k) {
                    f4 v = hv1[k];
                    f2 lo = (f2){v.x, v.y}, hi = (f2){v.z, v.w};
                    aA += v1a[2*k] * lo;  aA += v1a[2*k+1] * hi;
                    aB += v1b[2*k] * lo;  aB += v1b[2*k+1] * hi;
                }
                zp1[e][b][r]       = aA.x + aA.y;
                zp1[e][b][r + 128] = aB.x + aB.y;
            }
        }
        // x staging for t+1 (overlaps GEMV tail)
        if (t < TT - 1 && tid < NB * II) {
            xs[nxt][lrow][lcol] = pre;
            int tn = (t + 2 < TT) ? t + 2 : TT - 1;
            pre = xrow[(size_t)tn * II];
        }
        __syncthreads();   // bar1: zp*/h* handoff to combine

        // ---- fused combine: waves 0-3 -> cell0(t), waves 4-7 -> cell1(t-1) ----
        if (tid < 512) {
            const bool act = lay ? (t >= 1) : (t < TT);   // wave-uniform
            if (act) {
                float (*zp)[NB][G4] = lay ? zp1 : zp0;
                float zi = bi_r, zf = bf_r, zg = bg_r, zo = bo_r;
                #pragma unroll
                for (int p = 0; p < SK; ++p) {
                    zi += zp[p][cb][cj];
                    zf += zp[p][cb][64 + cj];
                    zg += zp[p][cb][128 + cj];
                    zo += zp[p][cb][192 + cj];
                }
                float gi = sigm(zi), gf = sigm(zf), gg = tanh_f(zg), go = sigm(zo);
                c_reg = gf * c_reg + gi * gg;
                float h = go * tanh_f(c_reg);
                if (lay == 0) h0s[cb][cj] = h;
                else          h1s[cb][cj] = h;
            }
        }
        __syncthreads();   // bar2: h* handoff to next GEMV / zp* reuse
    }
#undef PIN

    // lay-1 combine thread wrote h1s[cb][cj] itself at t=TT -> read-own-write
    if (tid >= 256 && tid < 512)
        hlast[(size_t)(b0 + cb) * HH + cj] = h1s[cb][cj];
}

// MLP head: one block per batch row. relu(hW_p^T+b) -> relu(.W_1^T+b) -> .W_2^T+b
__global__ __launch_bounds__(128, 4)
void head_kernel(const float* __restrict__ hlast,
                 const float* __restrict__ Wp, const float* __restrict__ bp,
                 const float* __restrict__ W1, const float* __restrict__ b1,
                 const float* __restrict__ W2, const float* __restrict__ b2,
                 float* __restrict__ out)
{
    __shared__ float hv[HH];
    __shared__ float emb[EE];
    __shared__ float hid[EE];
    const int b = blockIdx.x;
    const int e = threadIdx.x;   // 0..127
    if (e < HH) hv[e] = hlast[(size_t)b * HH + e];
    __syncthreads();
    float z = bp[e];
    #pragma unroll
    for (int j = 0; j < HH; ++j) z += Wp[e * HH + j] * hv[j];
    emb[e] = fmaxf(z, 0.f);
    __syncthreads();
    z = b1[e];
    #pragma unroll
    for (int j = 0; j < EE; ++j) z += W1[e * EE + j] * emb[j];
    hid[e] = fmaxf(z, 0.f);
    __syncthreads();
    if (e < CC) {
        z = b2[e];
        #pragma unroll
        for (int j = 0; j < EE; ++j) z += W2[e * EE + j] * hid[j];
        out[(size_t)b * CC + e] = z;
    }
}

extern "C" void kernel_launch(void* const* d_in, const int* in_sizes, int n_in,
                              void* d_out, int out_size, void* d_ws, size_t ws_size,
                              hipStream_t stream)
{
    const float* x    = (const float*)d_in[0];
    const float* Wih0 = (const float*)d_in[1];
    const float* Whh0 = (const float*)d_in[2];
    const float* bih0 = (const float*)d_in[3];
    const float* bhh0 = (const float*)d_in[4];
    const float* Wih1 = (const float*)d_in[5];
    const float* Whh1 = (const float*)d_in[6];
    const float* bih1 = (const float*)d_in[7];
    const float* bhh1 = (const float*)d_in[8];
    const float* Wp   = (const float*)d_in[9];
    const float* bp   = (const float*)d_in[10];
    const float* W1   = (const float*)d_in[11];
    const float* b1   = (const float*)d_in[12];
    const float* W2   = (const float*)d_in[13];
    const float* b2   = (const float*)d_in[14];

    float* hlast = (float*)d_ws;           // 1024*64 fp32 = 256 KB
    float* out   = (float*)d_out;          // [1024, 100] fp32

    lstm2_persistent<<<BB / NB, NTH, 0, stream>>>(x, Wih0, Whh0, bih0, bhh0,
                                                  Wih1, Whh1, bih1, bhh1, hlast);
    head_kernel<<<BB, EE, 0, stream>>>(hlast, Wp, bp, W1, b1, W2, b2, out);
}